// Round 7
// baseline (137.166 us; speedup 1.0000x reference)
//
#include <hip/hip_runtime.h>

// Single-scale fixed-size deformable attention.
// value:  (BS, H*W, NH, HD) f32
// sloc:   (BS, NQ, NH, 1, NP, 2) f32  (locations in [0,1])
// aw:     (BS, NQ, NH, 1, NP) f32
// out:    (BS, NQ, NH*HD) f32
//
// R4: 68.7us FETCH 226MB. R5 (XCD slab swizzle, 1 group/thread): 51.5us,
// FETCH 54.7MB (compulsory). R6 (4 slabs concurrent/XCD): 54.9us FETCH 97MB
// -- slab thrash, working set 5.12MB > 4MB L2. R7: R5 ordering exactly,
// 2 groups/thread paired WITHIN one slab (q, q+5000) -> 2x MLP, working set
// still 1 slab (1.28MB).

constexpr int BS = 4, NQ = 10000, NH = 8, HD = 32, NP = 4, H = 100, W = 100;
constexpr int HW = H * W;
constexpr int NQH = NQ / 2;                     // 5000

typedef float f32x4 __attribute__((ext_vector_type(4)));

__device__ __forceinline__ void bilinear_accum(const float lx[NP], const float ly[NP],
                                               const float wp[NP],
                                               const float* __restrict__ vbase,
                                               f32x4& acc)
{
#pragma unroll
    for (int p = 0; p < NP; ++p) {
        const float x = lx[p] * (float)W - 0.5f;
        const float y = ly[p] * (float)H - 0.5f;
        const float x0f = floorf(x);
        const float y0f = floorf(y);
        const int   x0  = (int)x0f, y0 = (int)y0f;
        const int   x1  = x0 + 1,   y1 = y0 + 1;
        const float wx1 = x - x0f,  wx0 = 1.f - wx1;
        const float wy1 = y - y0f,  wy0 = 1.f - wy1;

        const bool vx0 = (unsigned)x0 < (unsigned)W;
        const bool vx1 = (unsigned)x1 < (unsigned)W;
        const bool vy0 = (unsigned)y0 < (unsigned)H;
        const bool vy1 = (unsigned)y1 < (unsigned)H;

        const int xc0 = min(max(x0, 0), W - 1);
        const int xc1 = min(max(x1, 0), W - 1);
        const int yc0 = min(max(y0, 0), H - 1);
        const int yc1 = min(max(y1, 0), H - 1);

        // zeros padding: invalid corner -> weight 0 (load stays in-bounds via clamp)
        const float w00 = (vx0 && vy0) ? wp[p] * wx0 * wy0 : 0.f;
        const float w10 = (vx1 && vy0) ? wp[p] * wx1 * wy0 : 0.f;
        const float w01 = (vx0 && vy1) ? wp[p] * wx0 * wy1 : 0.f;
        const float w11 = (vx1 && vy1) ? wp[p] * wx1 * wy1 : 0.f;

        const f32x4 v00 = *(const f32x4*)(vbase + (size_t)(yc0 * W + xc0) * (NH * HD));
        const f32x4 v10 = *(const f32x4*)(vbase + (size_t)(yc0 * W + xc1) * (NH * HD));
        const f32x4 v01 = *(const f32x4*)(vbase + (size_t)(yc1 * W + xc0) * (NH * HD));
        const f32x4 v11 = *(const f32x4*)(vbase + (size_t)(yc1 * W + xc1) * (NH * HD));

        acc += w00 * v00 + w10 * v10 + w01 * v01 + w11 * v11;
    }
}

__global__ __launch_bounds__(256)
void deform_attn_kernel(const float* __restrict__ value,
                        const float* __restrict__ sloc,
                        const float* __restrict__ aw,
                        float* __restrict__ out)
{
    // XCD chunk swizzle: grid=5000, chunk=625. XCD x gets logical blocks
    // [x*625,(x+1)*625) -> half-group range [x*20000,(x+1)*20000) -> bh range
    // [4x, 4x+4): 4 slabs, streamed SEQUENTIALLY (q-minor), 1.28MB window.
    const int chunk = 625;
    const int swz   = (blockIdx.x & 7) * chunk + (blockIdx.x >> 3);

    const int tid  = swz * 256 + (int)threadIdx.x;
    const int hg   = tid >> 3;                  // half-group: bh*NQH + qh
    const int lane = tid & 7;                   // channel quad (16B)

    const int qh = hg % NQH;                    // q in [0,5000) (magic-mul)
    const int bh = hg / NQH;                    // b*NH + h
    const int h  = bh & (NH - 1);
    const int b  = bh >> 3;

    const int bq1 = b * NQ + qh;                // group 1: (b, qh,      h)
    const int bq2 = bq1 + NQH;                  // group 2: (b, qh+5000, h)

    // Params for both groups up front -> 6 independent loads in flight.
    const size_t p1 = (size_t)bq1 * NH + h;
    const size_t p2 = (size_t)bq2 * NH + h;
    const f32x4 a01 = *(const f32x4*)(sloc + p1 * (NP * 2));
    const f32x4 a23 = *(const f32x4*)(sloc + p1 * (NP * 2) + 4);
    const f32x4 awa = *(const f32x4*)(aw   + p1 * NP);
    const f32x4 b01 = *(const f32x4*)(sloc + p2 * (NP * 2));
    const f32x4 b23 = *(const f32x4*)(sloc + p2 * (NP * 2) + 4);
    const f32x4 awb = *(const f32x4*)(aw   + p2 * NP);

    const float lxa[NP] = {a01.x, a01.z, a23.x, a23.z};
    const float lya[NP] = {a01.y, a01.w, a23.y, a23.w};
    const float wpa[NP] = {awa.x, awa.y, awa.z, awa.w};
    const float lxb[NP] = {b01.x, b01.z, b23.x, b23.z};
    const float lyb[NP] = {b01.y, b01.w, b23.y, b23.w};
    const float wpb[NP] = {awb.x, awb.y, awb.z, awb.w};

    // Same (b,h) slab for both groups.
    const float* vbase = value + (size_t)b * HW * NH * HD + h * HD + lane * 4;

    f32x4 acc1 = (f32x4)(0.f);
    f32x4 acc2 = (f32x4)(0.f);
    bilinear_accum(lxa, lya, wpa, vbase, acc1);
    bilinear_accum(lxb, lyb, wpb, vbase, acc2);

    // Line-exact 128B stores (8 lanes x 16B), nontemporal (write-once).
    __builtin_nontemporal_store(acc1, (f32x4*)(out + (size_t)bq1 * (NH * HD) + h * HD + lane * 4));
    __builtin_nontemporal_store(acc2, (f32x4*)(out + (size_t)bq2 * (NH * HD) + h * HD + lane * 4));
}

extern "C" void kernel_launch(void* const* d_in, const int* in_sizes, int n_in,
                              void* d_out, int out_size, void* d_ws, size_t ws_size,
                              hipStream_t stream) {
    const float* value = (const float*)d_in[0];
    // d_in[1] = value_spatial_shapes (int64) — unused in fixed-size variant
    const float* sloc  = (const float*)d_in[2];
    const float* aw    = (const float*)d_in[3];
    float*       out   = (float*)d_out;

    // 5000 blocks x 256 threads x 2 groups/thread = 320,000 groups
    deform_attn_kernel<<<5000, 256, 0, stream>>>(value, sloc, aw, out);
}

// Round 8
// 134.279 us; speedup vs baseline: 1.0215x; 1.0215x over previous
//
#include <hip/hip_runtime.h>

// Single-scale fixed-size deformable attention.
// value:  (BS, H*W, NH, HD) f32
// sloc:   (BS, NQ, NH, 1, NP, 2) f32  (locations in [0,1])
// aw:     (BS, NQ, NH, 1, NP) f32
// out:    (BS, NQ, NH*HD) f32
//
// R4: 68.7us FETCH 226MB. R5 (XCD slab swizzle): 51.5us FETCH 54.7MB
// (compulsory). R6: slab thrash (-). R7 (2 groups/thread): 54us, VGPR stuck
// at 32 -> compiler serialized loads, MLP never doubled.
// R8: explicit 16-gather hoist into register array + __launch_bounds__(256,4)
// (VGPR cap 128) -> all 16 corner loads in flight per thread.

constexpr int BS = 4, NQ = 10000, NH = 8, HD = 32, NP = 4, H = 100, W = 100;
constexpr int HW = H * W;

typedef float f32x4 __attribute__((ext_vector_type(4)));

__global__ __launch_bounds__(256, 4)
void deform_attn_kernel(const float* __restrict__ value,
                        const float* __restrict__ sloc,
                        const float* __restrict__ aw,
                        float* __restrict__ out)
{
    // XCD chunk swizzle (R5): grid=10000, chunk=1250. XCD x gets logical
    // blocks [x*1250,(x+1)*1250) = 4 (b,h) slabs streamed sequentially
    // (q-minor) -> concurrent working set ~1.28MB < 4MB XCD L2.
    const int chunk = gridDim.x >> 3;                    // 1250
    const int swz   = (blockIdx.x & 7) * chunk + (blockIdx.x >> 3);

    const int tid   = swz * 256 + (int)threadIdx.x;
    const int group = tid >> 3;                          // bh*NQ + q
    const int lane  = tid & 7;                           // channel quad (16B)

    const int q  = group % NQ;                           // magic-mul
    const int bh = group / NQ;                           // b*NH + h
    const int h  = bh & (NH - 1);
    const int b  = bh >> 3;
    const int bq = b * NQ + q;

    // Per-group params (8 lanes broadcast-share each 16B load).
    const size_t pbase = (size_t)bq * NH + h;
    const f32x4 l01 = *(const f32x4*)(sloc + pbase * (NP * 2));
    const f32x4 l23 = *(const f32x4*)(sloc + pbase * (NP * 2) + 4);
    const f32x4 wv  = *(const f32x4*)(aw   + pbase * NP);

    const float lx[NP] = {l01.x, l01.z, l23.x, l23.z};
    const float ly[NP] = {l01.y, l01.w, l23.y, l23.w};
    const float wp[NP] = {wv.x,  wv.y,  wv.z,  wv.w};

    const float* vbase = value + (size_t)b * HW * NH * HD + h * HD + lane * 4;

    // Phase 1: all 16 offsets + 16 weights (no loads yet).
    int   offs[NP][4];
    float wgt [NP][4];
#pragma unroll
    for (int p = 0; p < NP; ++p) {
        // grid = 2*loc-1; unnormalize align_corners=False: x = loc*W - 0.5
        const float x = lx[p] * (float)W - 0.5f;
        const float y = ly[p] * (float)H - 0.5f;
        const float x0f = floorf(x);
        const float y0f = floorf(y);
        const int   x0  = (int)x0f, y0 = (int)y0f;
        const int   x1  = x0 + 1,   y1 = y0 + 1;
        const float wx1 = x - x0f,  wx0 = 1.f - wx1;
        const float wy1 = y - y0f,  wy0 = 1.f - wy1;

        const bool vx0 = (unsigned)x0 < (unsigned)W;
        const bool vx1 = (unsigned)x1 < (unsigned)W;
        const bool vy0 = (unsigned)y0 < (unsigned)H;
        const bool vy1 = (unsigned)y1 < (unsigned)H;

        const int xc0 = min(max(x0, 0), W - 1);
        const int xc1 = min(max(x1, 0), W - 1);
        const int yc0 = min(max(y0, 0), H - 1);
        const int yc1 = min(max(y1, 0), H - 1);

        offs[p][0] = yc0 * W + xc0;
        offs[p][1] = yc0 * W + xc1;
        offs[p][2] = yc1 * W + xc0;
        offs[p][3] = yc1 * W + xc1;

        // zeros padding: invalid corner -> weight 0 (clamped load stays in-bounds)
        wgt[p][0] = (vx0 && vy0) ? wp[p] * wx0 * wy0 : 0.f;
        wgt[p][1] = (vx1 && vy0) ? wp[p] * wx1 * wy0 : 0.f;
        wgt[p][2] = (vx0 && vy1) ? wp[p] * wx0 * wy1 : 0.f;
        wgt[p][3] = (vx1 && vy1) ? wp[p] * wx1 * wy1 : 0.f;
    }

    // Phase 2: issue ALL 16 gathers back-to-back (64 VGPRs of payload in
    // flight; launch_bounds gives the 128-VGPR headroom).
    f32x4 v[NP][4];
#pragma unroll
    for (int p = 0; p < NP; ++p)
#pragma unroll
        for (int c = 0; c < 4; ++c)
            v[p][c] = *(const f32x4*)(vbase + (size_t)offs[p][c] * (NH * HD));

    // Phase 3: reduce.
    f32x4 acc = (f32x4)(0.f);
#pragma unroll
    for (int p = 0; p < NP; ++p)
#pragma unroll
        for (int c = 0; c < 4; ++c)
            acc += wgt[p][c] * v[p][c];

    // Line-exact 128B store (8 lanes x 16B), nontemporal (write-once).
    __builtin_nontemporal_store(acc, (f32x4*)(out + (size_t)bq * (NH * HD) + h * HD + lane * 4));
}

extern "C" void kernel_launch(void* const* d_in, const int* in_sizes, int n_in,
                              void* d_out, int out_size, void* d_ws, size_t ws_size,
                              hipStream_t stream) {
    const float* value = (const float*)d_in[0];
    // d_in[1] = value_spatial_shapes (int64) — unused in fixed-size variant
    const float* sloc  = (const float*)d_in[2];
    const float* aw    = (const float*)d_in[3];
    float*       out   = (float*)d_out;

    // 10000 blocks x 256 threads = 2,560,000 threads = NGROUP*8 exactly
    deform_attn_kernel<<<10000, 256, 0, stream>>>(value, sloc, aw, out);
}

// Round 9
// 130.292 us; speedup vs baseline: 1.0528x; 1.0306x over previous
//
#include <hip/hip_runtime.h>

// Single-scale fixed-size deformable attention.
// value:  (BS, H*W, NH, HD) f32; sloc: (BS,NQ,NH,1,NP,2); aw: (BS,NQ,NH,1,NP)
// out:    (BS, NQ, NH*HD) f32
//
// R5 (XCD slab swizzle): 51.5us, FETCH=compulsory 54.7MB, VALU 27% -> nothing
// saturated; concurrency-limited (Little's law: ~80 lines in flight/CU).
// R7/R8: compiler re-serialized loads (VGPR stuck at 32/36) -> MLP never rose.
// R9: inline-asm SRSRC buffer_load_dwordx4 x16 back-to-back + staged
// s_waitcnt vmcnt(12/8/4/0) consumption. Compiler cannot reschedule volatile
// asm -> true 16-deep MLP per thread.

constexpr int BS = 4, NQ = 10000, NH = 8, HD = 32, NP = 4, H = 100, W = 100;
constexpr int HW = H * W;
constexpr unsigned VBYTES = (unsigned)BS * HW * NH * HD * 4u;  // 40,960,000

typedef float    f32x4 __attribute__((ext_vector_type(4)));
typedef unsigned u32x4 __attribute__((ext_vector_type(4)));

__global__ __launch_bounds__(256, 4)
void deform_attn_kernel(const float* __restrict__ value,
                        const float* __restrict__ sloc,
                        const float* __restrict__ aw,
                        float* __restrict__ out)
{
    // XCD chunk swizzle (R5-verified): XCD x gets 4 (b,h) slabs streamed
    // sequentially; concurrent working set ~1.28MB < 4MB XCD L2.
    const int chunk = gridDim.x >> 3;                    // 1250
    const int swz   = (blockIdx.x & 7) * chunk + (blockIdx.x >> 3);

    const int tid   = swz * 256 + (int)threadIdx.x;
    const int group = tid >> 3;                          // bh*NQ + q
    const int lane  = tid & 7;                           // channel quad (16B)

    const int q  = group % NQ;                           // magic-mul
    const int bh = group / NQ;
    const int h  = bh & (NH - 1);
    const int b  = bh >> 3;
    const int bq = b * NQ + q;

    // Per-group params (8 lanes broadcast-share each 16B load).
    const size_t pbase = (size_t)bq * NH + h;
    const f32x4 l01 = *(const f32x4*)(sloc + pbase * (NP * 2));
    const f32x4 l23 = *(const f32x4*)(sloc + pbase * (NP * 2) + 4);
    const f32x4 wv  = *(const f32x4*)(aw   + pbase * NP);

    const float lx[NP] = {l01.x, l01.z, l23.x, l23.z};
    const float ly[NP] = {l01.y, l01.w, l23.y, l23.w};
    const float wp[NP] = {wv.x,  wv.y,  wv.z,  wv.w};

    // ---- Phase 1: 16 byte-voffsets (32-bit; value is 40.96MB < 4GB) ----
    const unsigned chan = (unsigned)(h * HD + lane * 4) * 4u;   // channel byte off
    const unsigned pixb = (unsigned)(b * HW);
    unsigned voff[NP][4];
    float    wx0s[NP], wx1s[NP], wy0s[NP], wy1s[NP];
    bool     vx0s[NP], vx1s[NP], vy0s[NP], vy1s[NP];
#pragma unroll
    for (int p = 0; p < NP; ++p) {
        const float x = lx[p] * (float)W - 0.5f;   // align_corners=False unnorm
        const float y = ly[p] * (float)H - 0.5f;
        const float x0f = floorf(x);
        const float y0f = floorf(y);
        const int   x0  = (int)x0f, y0 = (int)y0f;
        const int   x1  = x0 + 1,   y1 = y0 + 1;
        wx1s[p] = x - x0f; wx0s[p] = 1.f - wx1s[p];
        wy1s[p] = y - y0f; wy0s[p] = 1.f - wy1s[p];
        vx0s[p] = (unsigned)x0 < (unsigned)W;
        vx1s[p] = (unsigned)x1 < (unsigned)W;
        vy0s[p] = (unsigned)y0 < (unsigned)H;
        vy1s[p] = (unsigned)y1 < (unsigned)H;
        const unsigned xc0 = (unsigned)min(max(x0, 0), W - 1);
        const unsigned xc1 = (unsigned)min(max(x1, 0), W - 1);
        const unsigned yc0 = (unsigned)min(max(y0, 0), H - 1);
        const unsigned yc1 = (unsigned)min(max(y1, 0), H - 1);
        voff[p][0] = (pixb + yc0 * W + xc0) * 1024u + chan;
        voff[p][1] = (pixb + yc0 * W + xc1) * 1024u + chan;
        voff[p][2] = (pixb + yc1 * W + xc0) * 1024u + chan;
        voff[p][3] = (pixb + yc1 * W + xc1) * 1024u + chan;
    }

    // ---- SRSRC for the whole value tensor ----
    union { const float* p; unsigned u[2]; } va; va.p = value;
    const u32x4 rsrc = {va.u[0], va.u[1] & 0xFFFFu, VBYTES, 0x00020000u};

    // ---- Phase 2: issue ALL 16 gathers back-to-back (volatile asm: the
    // backend cannot sink/serialize them). 64 payload VGPRs in flight. ----
    f32x4 v00,v01,v02,v03, v10,v11,v12,v13, v20,v21,v22,v23, v30,v31,v32,v33;
#define GLOAD(dst, off) \
    asm volatile("buffer_load_dwordx4 %0, %1, %2, 0 offen" \
                 : "=v"(dst) : "v"(off), "s"(rsrc))
    GLOAD(v00, voff[0][0]); GLOAD(v01, voff[0][1]); GLOAD(v02, voff[0][2]); GLOAD(v03, voff[0][3]);
    GLOAD(v10, voff[1][0]); GLOAD(v11, voff[1][1]); GLOAD(v12, voff[1][2]); GLOAD(v13, voff[1][3]);
    GLOAD(v20, voff[2][0]); GLOAD(v21, voff[2][1]); GLOAD(v22, voff[2][2]); GLOAD(v23, voff[2][3]);
    GLOAD(v30, voff[3][0]); GLOAD(v31, voff[3][1]); GLOAD(v32, voff[3][2]); GLOAD(v33, voff[3][3]);
#undef GLOAD

    // ---- Phase 3: weights, computed UNDER the load latency ----
    float wgt[NP][4];
#pragma unroll
    for (int p = 0; p < NP; ++p) {
        wgt[p][0] = (vx0s[p] && vy0s[p]) ? wp[p] * wx0s[p] * wy0s[p] : 0.f;
        wgt[p][1] = (vx1s[p] && vy0s[p]) ? wp[p] * wx1s[p] * wy0s[p] : 0.f;
        wgt[p][2] = (vx0s[p] && vy1s[p]) ? wp[p] * wx0s[p] * wy1s[p] : 0.f;
        wgt[p][3] = (vx1s[p] && vy1s[p]) ? wp[p] * wx1s[p] * wy1s[p] : 0.f;
    }

    // ---- Phase 4: staged consumption. "+v" ties make the FMAs data-depend
    // on the waitcnt asm so they cannot hoist above it (guide rule #18). ----
    f32x4 acc = (f32x4)(0.f);
    asm volatile("s_waitcnt vmcnt(12)" : "+v"(v00), "+v"(v01), "+v"(v02), "+v"(v03));
    acc += wgt[0][0]*v00 + wgt[0][1]*v01 + wgt[0][2]*v02 + wgt[0][3]*v03;
    asm volatile("s_waitcnt vmcnt(8)"  : "+v"(v10), "+v"(v11), "+v"(v12), "+v"(v13));
    acc += wgt[1][0]*v10 + wgt[1][1]*v11 + wgt[1][2]*v12 + wgt[1][3]*v13;
    asm volatile("s_waitcnt vmcnt(4)"  : "+v"(v20), "+v"(v21), "+v"(v22), "+v"(v23));
    acc += wgt[2][0]*v20 + wgt[2][1]*v21 + wgt[2][2]*v22 + wgt[2][3]*v23;
    asm volatile("s_waitcnt vmcnt(0)"  : "+v"(v30), "+v"(v31), "+v"(v32), "+v"(v33));
    acc += wgt[3][0]*v30 + wgt[3][1]*v31 + wgt[3][2]*v32 + wgt[3][3]*v33;

    // Line-exact 128B store (8 lanes x 16B), nontemporal (write-once).
    __builtin_nontemporal_store(acc, (f32x4*)(out + (size_t)bq * (NH * HD) + h * HD + lane * 4));
}

extern "C" void kernel_launch(void* const* d_in, const int* in_sizes, int n_in,
                              void* d_out, int out_size, void* d_ws, size_t ws_size,
                              hipStream_t stream) {
    const float* value = (const float*)d_in[0];
    // d_in[1] = value_spatial_shapes (int64) — unused in fixed-size variant
    const float* sloc  = (const float*)d_in[2];
    const float* aw    = (const float*)d_in[3];
    float*       out   = (float*)d_out;

    deform_attn_kernel<<<10000, 256, 0, stream>>>(value, sloc, aw, out);
}

// Round 10
// 125.012 us; speedup vs baseline: 1.0972x; 1.0422x over previous
//
#include <hip/hip_runtime.h>

// Single-scale fixed-size deformable attention.
// value: (BS,H*W,NH,HD) f32; sloc: (BS,NQ,NH,1,NP,2); aw: (BS,NQ,NH,1,NP)
// out:   (BS,NQ,NH*HD) f32
//
// R5: 51.5us FETCH=compulsory. R9 (forced 16-deep MLP): 47.5us -- L2-side
// gather service pinned at ~13.8 TB/s regardless of waves x MLP => hard
// random-128B cap. 655MB / 13.8TB/s = 47.5us exactly.
// R10: halve the stream. Pass1 casts value to fp16 in ws, transposed to
// (b,h,y,x,c) so the (x0,x1) corner pair is 128B contiguous -> one
// buffer_load_dwordx4 per pair per 8-lane group. bytes 0.5x, lines 0.625x,
// requests 0.5x. Cross-lane shfl_xor(4) combines x0/x1 partials.

constexpr int BS = 4, NQ = 10000, NH = 8, HD = 32, NP = 4, H = 100, W = 100;
constexpr int HW = H * W;
constexpr unsigned VBYTES_F32 = (unsigned)BS * HW * NH * HD * 4u;  // 40,960,000
constexpr unsigned VH_BYTES   = (unsigned)BS * HW * NH * HD * 2u;  // 20,480,000

typedef float    f32x4 __attribute__((ext_vector_type(4)));
typedef float    f32x8 __attribute__((ext_vector_type(8)));
typedef _Float16 f16x8 __attribute__((ext_vector_type(8)));
typedef unsigned u32x4 __attribute__((ext_vector_type(4)));

// ---- Pass 1: cast + transpose value (b,pix,h,c) f32 -> (b,h,y,x,c) fp16 ----
__global__ __launch_bounds__(256)
void cast_kernel(const float* __restrict__ v, _Float16* __restrict__ vh)
{
    const int tid = blockIdx.x * 256 + (int)threadIdx.x;   // exactly 1,280,000
    const int c8 = tid & 3;            // which 8-channel chunk
    const int t2 = tid >> 2;
    const int x  = t2 % 100;
    const int t3 = t2 / 100;
    const int y  = t3 % 100;
    const int t4 = t3 / 100;           // b*8 + h
    const float* src = v + ((size_t)(t4 >> 3) * HW + y * W + x) * 256 + (t4 & 7) * 32 + c8 * 8;
    const f32x4 a = __builtin_nontemporal_load((const f32x4*)src);
    const f32x4 b = __builtin_nontemporal_load((const f32x4*)(src + 4));
    const f32x8 f = {a.x, a.y, a.z, a.w, b.x, b.y, b.z, b.w};
    const f16x8 o = __builtin_convertvector(f, f16x8);
    *(f16x8*)(vh + ((size_t)t4 * HW + y * W + x) * 32 + c8 * 8) = o;  // cacheable: read next kernel
}

// ---- Pass 2: paired-corner fp16 gather ----
__global__ __launch_bounds__(256, 4)
void gather_kernel(const _Float16* __restrict__ vh,
                   const float* __restrict__ sloc,
                   const float* __restrict__ aw,
                   float* __restrict__ out)
{
    // XCD slab swizzle (R5-verified): XCD x streams 4 (b,h) slabs sequentially.
    const int chunk = gridDim.x >> 3;                    // 1250
    const int swz   = (blockIdx.x & 7) * chunk + (blockIdx.x >> 3);

    const int tid   = swz * 256 + (int)threadIdx.x;
    const int group = tid >> 3;                          // bh*NQ + q
    const int lane  = tid & 7;
    const int xsel  = lane >> 2;                         // 0: x0-corner, 1: x1-corner
    const int csel  = lane & 3;                          // 8-channel chunk (16B fp16)

    const int q  = group % NQ;                           // magic-mul
    const int bh = group / NQ;
    const int h  = bh & (NH - 1);
    const int b  = bh >> 3;
    const int bq = b * NQ + q;

    // Per-group params (broadcast 16B loads).
    const size_t pbase = (size_t)bq * NH + h;
    const f32x4 l01 = *(const f32x4*)(sloc + pbase * (NP * 2));
    const f32x4 l23 = *(const f32x4*)(sloc + pbase * (NP * 2) + 4);
    const f32x4 wv  = *(const f32x4*)(aw   + pbase * NP);

    const float lx[NP] = {l01.x, l01.z, l23.x, l23.z};
    const float ly[NP] = {l01.y, l01.w, l23.y, l23.w};
    const float wp[NP] = {wv.x,  wv.y,  wv.z,  wv.w};

    const unsigned slabbase = (unsigned)(bh * HW) * 64u;   // 64B per pixel (fp16)

    // Offsets + weights for 8 pair-loads (4 points x 2 rows).
    unsigned voff[NP][2];
    float    wrow[NP][2];       // fy weight per row (0 if row invalid)
    float    wxl[NP];           // this lane's x-weight * aw (0 if x invalid)
#pragma unroll
    for (int p = 0; p < NP; ++p) {
        const float x = lx[p] * (float)W - 0.5f;    // align_corners=False unnorm
        const float y = ly[p] * (float)H - 0.5f;
        const float x0f = floorf(x);
        const float y0f = floorf(y);
        const int   x0  = (int)x0f, y0 = (int)y0f;
        const float fx1 = x - x0f, fx0 = 1.f - fx1;
        const float fy1 = y - y0f, fy0 = 1.f - fy1;

        const int xc = x0 + xsel;                   // lane's x corner
        wxl[p] = ((unsigned)xc < (unsigned)W) ? (xsel ? fx1 : fx0) * wp[p] : 0.f;
        wrow[p][0] = ((unsigned)y0 < (unsigned)H)       ? fy0 : 0.f;
        wrow[p][1] = ((unsigned)(y0 + 1) < (unsigned)H) ? fy1 : 0.f;

        const int basex = min(max(x0, 0), W - 2);   // pair base: [basex, basex+1]
        const int sl    = min(max(xc, 0), W - 1) - basex;   // lane slot 0/1
        const int y0c   = min(max(y0, 0), H - 1);
        const int y1c   = min(max(y0 + 1, 0), H - 1);
        const unsigned lo = (unsigned)(basex) * 64u + (unsigned)sl * 64u + (unsigned)csel * 16u;
        voff[p][0] = slabbase + (unsigned)(y0c * W) * 64u + lo;
        voff[p][1] = slabbase + (unsigned)(y1c * W) * 64u + lo;
    }

    // SRSRC over the fp16 value copy.
    union { const _Float16* p; unsigned u[2]; } va; va.p = vh;
    const u32x4 rsrc = {va.u[0], va.u[1] & 0xFFFFu, VH_BYTES, 0x00020000u};

    // Issue all 8 pair-loads back-to-back (volatile: cannot be re-serialized).
    f32x4 r00, r01, r10, r11, r20, r21, r30, r31;
#define GLOAD(dst, off) \
    asm volatile("buffer_load_dwordx4 %0, %1, %2, 0 offen" \
                 : "=v"(dst) : "v"(off), "s"(rsrc))
    GLOAD(r00, voff[0][0]); GLOAD(r01, voff[0][1]);
    GLOAD(r10, voff[1][0]); GLOAD(r11, voff[1][1]);
    GLOAD(r20, voff[2][0]); GLOAD(r21, voff[2][1]);
    GLOAD(r30, voff[3][0]); GLOAD(r31, voff[3][1]);
#undef GLOAD

    f32x8 acc = (f32x8)(0.f);
#define CONSUME(ra, rb, p, cnt) \
    asm volatile("s_waitcnt vmcnt(" #cnt ")" : "+v"(ra), "+v"(rb)); \
    { const f32x8 v0 = __builtin_convertvector(__builtin_bit_cast(f16x8, ra), f32x8); \
      const f32x8 v1 = __builtin_convertvector(__builtin_bit_cast(f16x8, rb), f32x8); \
      acc += v0 * (wxl[p] * wrow[p][0]) + v1 * (wxl[p] * wrow[p][1]); }
    CONSUME(r00, r01, 0, 6)
    CONSUME(r10, r11, 1, 4)
    CONSUME(r20, r21, 2, 2)
    CONSUME(r30, r31, 3, 0)
#undef CONSUME

    // Combine x0-partials (lanes 0-3) with x1-partials (lanes 4-7).
    f32x8 other;
#pragma unroll
    for (int j = 0; j < 8; ++j) other[j] = __shfl_xor(acc[j], 4, 8);
    acc += other;

    // Lane writes its 16B quarter: channels csel*8 + xsel*4 .. +4.
    const f32x4 res = xsel ? (f32x4){acc[4], acc[5], acc[6], acc[7]}
                           : (f32x4){acc[0], acc[1], acc[2], acc[3]};
    __builtin_nontemporal_store(res,
        (f32x4*)(out + (size_t)bq * (NH * HD) + h * HD + csel * 8 + xsel * 4));
}

// ---- Fallback (R9, f32 direct gather) if ws is too small ----
__global__ __launch_bounds__(256, 4)
void deform_attn_f32(const float* __restrict__ value,
                     const float* __restrict__ sloc,
                     const float* __restrict__ aw,
                     float* __restrict__ out)
{
    const int chunk = gridDim.x >> 3;
    const int swz   = (blockIdx.x & 7) * chunk + (blockIdx.x >> 3);
    const int tid   = swz * 256 + (int)threadIdx.x;
    const int group = tid >> 3;
    const int lane  = tid & 7;
    const int q  = group % NQ;
    const int bh = group / NQ;
    const int h  = bh & (NH - 1);
    const int b  = bh >> 3;
    const int bq = b * NQ + q;
    const size_t pbase = (size_t)bq * NH + h;
    const f32x4 l01 = *(const f32x4*)(sloc + pbase * (NP * 2));
    const f32x4 l23 = *(const f32x4*)(sloc + pbase * (NP * 2) + 4);
    const f32x4 wv  = *(const f32x4*)(aw   + pbase * NP);
    const float lx[NP] = {l01.x, l01.z, l23.x, l23.z};
    const float ly[NP] = {l01.y, l01.w, l23.y, l23.w};
    const float wp[NP] = {wv.x,  wv.y,  wv.z,  wv.w};
    const float* vbase = value + (size_t)b * HW * NH * HD + h * HD + lane * 4;
    f32x4 acc = (f32x4)(0.f);
#pragma unroll
    for (int p = 0; p < NP; ++p) {
        const float x = lx[p] * (float)W - 0.5f;
        const float y = ly[p] * (float)H - 0.5f;
        const float x0f = floorf(x), y0f = floorf(y);
        const int x0 = (int)x0f, y0 = (int)y0f, x1 = x0 + 1, y1 = y0 + 1;
        const float wx1 = x - x0f, wx0 = 1.f - wx1, wy1 = y - y0f, wy0 = 1.f - wy1;
        const bool vx0 = (unsigned)x0 < (unsigned)W, vx1 = (unsigned)x1 < (unsigned)W;
        const bool vy0 = (unsigned)y0 < (unsigned)H, vy1 = (unsigned)y1 < (unsigned)H;
        const int xc0 = min(max(x0, 0), W - 1), xc1 = min(max(x1, 0), W - 1);
        const int yc0 = min(max(y0, 0), H - 1), yc1 = min(max(y1, 0), H - 1);
        const float w00 = (vx0 && vy0) ? wp[p] * wx0 * wy0 : 0.f;
        const float w10 = (vx1 && vy0) ? wp[p] * wx1 * wy0 : 0.f;
        const float w01 = (vx0 && vy1) ? wp[p] * wx0 * wy1 : 0.f;
        const float w11 = (vx1 && vy1) ? wp[p] * wx1 * wy1 : 0.f;
        const f32x4 v00 = *(const f32x4*)(vbase + (size_t)(yc0 * W + xc0) * (NH * HD));
        const f32x4 v10 = *(const f32x4*)(vbase + (size_t)(yc0 * W + xc1) * (NH * HD));
        const f32x4 v01 = *(const f32x4*)(vbase + (size_t)(yc1 * W + xc0) * (NH * HD));
        const f32x4 v11 = *(const f32x4*)(vbase + (size_t)(yc1 * W + xc1) * (NH * HD));
        acc += w00 * v00 + w10 * v10 + w01 * v01 + w11 * v11;
    }
    __builtin_nontemporal_store(acc, (f32x4*)(out + (size_t)bq * (NH * HD) + h * HD + lane * 4));
}

extern "C" void kernel_launch(void* const* d_in, const int* in_sizes, int n_in,
                              void* d_out, int out_size, void* d_ws, size_t ws_size,
                              hipStream_t stream) {
    const float* value = (const float*)d_in[0];
    // d_in[1] = value_spatial_shapes (int64) — unused in fixed-size variant
    const float* sloc  = (const float*)d_in[2];
    const float* aw    = (const float*)d_in[3];
    float*       out   = (float*)d_out;

    if (ws_size >= (size_t)VH_BYTES) {
        _Float16* vh = (_Float16*)d_ws;
        cast_kernel<<<5000, 256, 0, stream>>>(value, vh);          // 1.28M threads
        gather_kernel<<<10000, 256, 0, stream>>>(vh, sloc, aw, out);
    } else {
        deform_attn_f32<<<10000, 256, 0, stream>>>(value, sloc, aw, out);
    }
}